// Round 14
// baseline (58.405 us; speedup 1.0000x reference)
//
#include <hip/hip_runtime.h>

typedef float f32x16 __attribute__((ext_vector_type(16)));
typedef short bf16x8 __attribute__((ext_vector_type(8)));

constexpr int SROWS  = 128;   // stationary rows per block (4 fragments)
constexpr int NSLICE = 1;     // full streaming range per block

__device__ inline short f2bf(float x) {               // RNE float->bf16 bits
    unsigned u = __float_as_uint(x);
    unsigned r = (u + 0x7fffu + ((u >> 16) & 1u)) >> 16;
    return (short)r;
}
__device__ inline float bf2f(short h) {
    return __uint_as_float(((unsigned)(unsigned short)h) << 16);
}
// min of 16 via min3-friendly tree (8 instrs)
__device__ inline float vmin16_t(f32x16 v) {
    float t1 = fminf(fminf(v[0], v[1]), v[2]);
    float t2 = fminf(fminf(v[3], v[4]), v[5]);
    float t3 = fminf(fminf(v[6], v[7]), v[8]);
    float t4 = fminf(fminf(v[9], v[10]), v[11]);
    float t5 = fminf(fminf(v[12], v[13]), v[14]);
    float u1 = fminf(fminf(t1, t2), t3);
    float u2 = fminf(fminf(t4, t5), v[15]);
    return fminf(u1, u2);
}

// K-slot map (k = 8*half + j), d = qw + pw - 2(qh+ql).(ph+pl) [ql.pl dropped]:
// A(query role) h0={-2qh(3), -2ql(3), qwh, qwl}  h1={-2qh(3), 1, 1, 0,0,0}
// B(point role) h0={ph(3), ph(3), 1, 1}          h1={pl(3), pwh, pwl, 0,0,0}
// Shared (half,j) slot space -> mapping-agnostic (r11-r13: absmax 0.0).
__global__ __launch_bounds__(256)
void chamfer_prep(const float* __restrict__ rec, const float* __restrict__ data,
                  bf16x8* __restrict__ Ar, bf16x8* __restrict__ Br,
                  bf16x8* __restrict__ Ad, bf16x8* __restrict__ Bd,
                  int N, int M, int B)
{
    const int i = blockIdx.x * 256 + threadIdx.x;
    const int tot0 = B * N, tot = tot0 + B * M;
    if (i >= tot) return;
    const short ONE = 0x3F80;
    const bool isRec = i < tot0;
    const int j = isRec ? i : i - tot0;
    const float* p = (isRec ? rec : data) + (size_t)j * 3;
    const float x = p[0], y = p[1], z = p[2];
    const float w = fmaf(x, x, fmaf(y, y, z * z));
    const short hx = f2bf(x), hy = f2bf(y), hz = f2bf(z);
    const float fx = bf2f(hx), fy = bf2f(hy), fz = bf2f(hz);
    const short nhx = f2bf(-2.f * fx), nhy = f2bf(-2.f * fy), nhz = f2bf(-2.f * fz);
    const short nlx = f2bf(-2.f * (x - fx));
    const short nly = f2bf(-2.f * (y - fy));
    const short nlz = f2bf(-2.f * (z - fz));
    const short lx = f2bf(x - fx), ly = f2bf(y - fy), lz = f2bf(z - fz);
    const short wh = f2bf(w);
    const short wl = f2bf(w - bf2f(wh));

    bf16x8 A0 = {nhx, nhy, nhz, nlx, nly, nlz, wh, wl};
    bf16x8 A1 = {nhx, nhy, nhz, ONE, ONE, 0, 0, 0};
    bf16x8 B0 = {hx, hy, hz, hx, hy, hz, ONE, ONE};
    bf16x8 B1 = {lx, ly, lz, wh, wl, 0, 0, 0};

    bf16x8* Adst = (isRec ? Ar : Ad) + 2 * (size_t)j;
    bf16x8* Bdst = (isRec ? Br : Bd) + 2 * (size_t)j;
    Adst[0] = A0; Adst[1] = A1;
    Bdst[0] = B0; Bdst[1] = B1;
}

// Stage 1: two symmetric passes (32x32x16 MFMA). launch_bounds(256,2) gives a
// 256 arch-VGPR budget so MFMA C/D live in arch VGPRs (no AGPR move storm —
// the r10-r13 phantom-VALU wall). "v"-constrained pins anchor the class:
// consumers read the pin's result, so it cannot be sunk (r5-r7 lesson).
__global__ __launch_bounds__(256, 2)
void chamfer_mfma_kernel(const bf16x8* __restrict__ Ar, const bf16x8* __restrict__ Bd,
                         const bf16x8* __restrict__ Ad, const bf16x8* __restrict__ Br,
                         float* __restrict__ part_data,   // [B][N/128][M]
                         float* __restrict__ part_rec,    // [B][M/128][N]
                         int N, int M, int B)
{
    const int nSB1 = N / SROWS;
    const int G1   = B * nSB1 * NSLICE;

    const bf16x8* Ap; const bf16x8* Bp; float* outp;
    int S, T, idx;
    if ((int)blockIdx.x < G1) {
        Ap = Ar; Bp = Bd; outp = part_data; S = N; T = M; idx = blockIdx.x;
    } else {
        Ap = Ad; Bp = Br; outp = part_rec;  S = M; T = N; idx = blockIdx.x - G1;
    }
    const int nSB = S / SROWS;
    const int sb  = idx % nSB;
    const int b   = idx / nSB;

    const int lane = threadIdx.x & 63, wave = threadIdx.x >> 6;
    const int c = lane & 31, h = lane >> 5;

    const bf16x8* __restrict__ Ab = Ap + 2 * ((size_t)b * S + sb * SROWS);
    const bf16x8* __restrict__ Bb = Bp + 2 * ((size_t)b * T);
    float* __restrict__ outBase = outp + ((size_t)b * nSB + sb) * T;

    bf16x8 a0 = Ab[2 * (0 * 32 + c) + h];
    bf16x8 a1 = Ab[2 * (1 * 32 + c) + h];
    bf16x8 a2 = Ab[2 * (2 * 32 + c) + h];
    bf16x8 a3 = Ab[2 * (3 * 32 + c) + h];

    f32x16 zacc;
    #pragma unroll
    for (int r = 0; r < 16; ++r) zacc[r] = 0.f;
    // volatile class-pin: zacc lives in arch VGPRs (MFMA C reads VGPR on gfx950)
    asm volatile("" : "+v"(zacc));

    const int TS32 = T >> 5;                     // 32-col tiles (full range)
    bf16x8 bcur = Bb[2 * ((size_t)wave * 32 + c) + h];
    for (int t = wave; t < TS32; t += 4) {
        int tn = t + 4; if (tn >= TS32) tn = wave;          // safe wrap
        bf16x8 bnext = Bb[2 * ((size_t)tn * 32 + c) + h];   // one-ahead prefetch

        f32x16 d0 = __builtin_amdgcn_mfma_f32_32x32x16_bf16(a0, bcur, zacc, 0, 0, 0);
        asm("" : "+v"(d0));    // D in arch VGPRs; consumers depend on pin
        f32x16 d1 = __builtin_amdgcn_mfma_f32_32x32x16_bf16(a1, bcur, zacc, 0, 0, 0);
        asm("" : "+v"(d1));
        f32x16 acc;
        #pragma unroll
        for (int r = 0; r < 16; ++r) acc[r] = fminf(d0[r], d1[r]);
        f32x16 d2 = __builtin_amdgcn_mfma_f32_32x32x16_bf16(a2, bcur, zacc, 0, 0, 0);
        asm("" : "+v"(d2));
        f32x16 d3 = __builtin_amdgcn_mfma_f32_32x32x16_bf16(a3, bcur, zacc, 0, 0, 0);
        asm("" : "+v"(d3));
        #pragma unroll
        for (int r = 0; r < 16; ++r)
            acc[r] = fminf(fminf(d2[r], d3[r]), acc[r]);    // v_min3

        float cm = vmin16_t(acc);                           // lane's 16 rows
        cm = fminf(cm, __shfl_xor(cm, 32));                 // merge h-halves: 128 rows
        if (lane < 32)
            outBase[(size_t)t * 32 + c] = cm;               // 128B coalesced store
        bcur = bnext;
    }
}

// Stage 2: per point, min over the nSB stationary-block partials, clamp, sum.
__global__ __launch_bounds__(256)
void chamfer_stage2(const float* __restrict__ part_data,
                    const float* __restrict__ part_rec,
                    float* __restrict__ bsums, int N, int M, int B)
{
    __shared__ float wsum[4];
    const int gid = blockIdx.x * 256 + threadIdx.x;
    const int nD = B * M;

    const float* base; size_t stride; int depth;
    if (gid < nD) {
        const int b = gid / M, col = gid - b * M;
        base = part_data + ((size_t)b * (N / SROWS)) * M + col;
        stride = M; depth = N / SROWS;
    } else {
        const int g = gid - nD;
        const int b = g / N, col = g - b * N;
        base = part_rec + ((size_t)b * (M / SROWS)) * N + col;
        stride = N; depth = M / SROWS;
    }
    float m0 = 3.4e38f, m1 = 3.4e38f, m2 = 3.4e38f, m3 = 3.4e38f;
    int s = 0;
    for (; s + 4 <= depth; s += 4) {
        m0 = fminf(m0, base[(s + 0) * stride]);
        m1 = fminf(m1, base[(s + 1) * stride]);
        m2 = fminf(m2, base[(s + 2) * stride]);
        m3 = fminf(m3, base[(s + 3) * stride]);
    }
    for (; s < depth; ++s) m0 = fminf(m0, base[s * stride]);
    float d = fmaxf(fminf(fminf(m0, m1), fminf(m2, m3)), 0.f);

    for (int off = 32; off; off >>= 1) d += __shfl_down(d, off);
    if ((threadIdx.x & 63) == 0) wsum[threadIdx.x >> 6] = d;
    __syncthreads();
    if (threadIdx.x == 0)
        bsums[blockIdx.x] = wsum[0] + wsum[1] + wsum[2] + wsum[3];
}

// Finalize: mean_b( max(recsum_b/N, datasum_b/M) )
__global__ __launch_bounds__(256)
void chamfer_finalize(const float* __restrict__ bsums, float* __restrict__ out,
                      int N, int M, int B)
{
    __shared__ float smem[512];
    __shared__ float seg[16];
    const int ncD = M >> 8, ncR = N >> 8;       // stage2 blocks per batch
    const int nD  = B * ncD, ntot = nD + B * ncR;
    const int tid = threadIdx.x;
    for (int i = tid; i < ntot; i += 256) smem[i] = bsums[i];
    __syncthreads();
    if (tid < 2 * B) {
        const int dir = tid / B, bb = tid % B;   // dir0 = data, dir1 = rec
        float s = 0.f;
        if (dir == 0) for (int i = 0; i < ncD; ++i) s += smem[bb * ncD + i];
        else          for (int i = 0; i < ncR; ++i) s += smem[nD + bb * ncR + i];
        seg[tid] = s;
    }
    __syncthreads();
    if (tid == 0) {
        float acc = 0.f;
        for (int bb = 0; bb < B; ++bb)
            acc += fmaxf(seg[B + bb] / (float)N, seg[bb] / (float)M);
        out[0] = acc / (float)B;
    }
}

extern "C" void kernel_launch(void* const* d_in, const int* in_sizes, int n_in,
                              void* d_out, int out_size, void* d_ws, size_t ws_size,
                              hipStream_t stream)
{
    const float* rec  = (const float*)d_in[0];
    const float* data = (const float*)d_in[1];
    const int B = 4;
    const int N = in_sizes[0] / (B * 3);
    const int M = in_sizes[1] / (B * 3);
    const int tot = B * (N + M);

    // ws: Ar 1MB | Br 1MB | Ad 1MB | Bd 1MB | part_data 8.4MB | part_rec 8.4MB
    char* w = (char*)d_ws;
    bf16x8* Ar = (bf16x8*)w;  w += (size_t)B * N * 2 * sizeof(bf16x8);
    bf16x8* Br = (bf16x8*)w;  w += (size_t)B * N * 2 * sizeof(bf16x8);
    bf16x8* Ad = (bf16x8*)w;  w += (size_t)B * M * 2 * sizeof(bf16x8);
    bf16x8* Bd = (bf16x8*)w;  w += (size_t)B * M * 2 * sizeof(bf16x8);
    float* part_data = (float*)w;  w += (size_t)B * (N / SROWS) * M * sizeof(float);
    float* part_rec  = (float*)w;  w += (size_t)B * (M / SROWS) * N * sizeof(float);
    float* bsums = (float*)w;

    chamfer_prep<<<(tot + 255) / 256, 256, 0, stream>>>(rec, data, Ar, Br, Ad, Bd,
                                                        N, M, B);
    const int G = B * (N / SROWS) * NSLICE + B * (M / SROWS) * NSLICE;  // 512
    chamfer_mfma_kernel<<<G, 256, 0, stream>>>(Ar, Bd, Ad, Br,
                                               part_data, part_rec, N, M, B);
    chamfer_stage2<<<tot / 256, 256, 0, stream>>>(part_data, part_rec, bsums,
                                                  N, M, B);
    chamfer_finalize<<<1, 256, 0, stream>>>(bsums, (float*)d_out, N, M, B);
}

// Round 15
// 41.193 us; speedup vs baseline: 1.4178x; 1.4178x over previous
//
#include <hip/hip_runtime.h>

typedef float f32x16 __attribute__((ext_vector_type(16)));
typedef short bf16x8 __attribute__((ext_vector_type(8)));

constexpr int SROWS  = 256;   // stationary rows per block (8 frags) - r12-best
constexpr int NSLICE = 4;     // streaming slices per pass -> grid 1024

__device__ inline short f2bf(float x) {               // RNE float->bf16 bits
    unsigned u = __float_as_uint(x);
    unsigned r = (u + 0x7fffu + ((u >> 16) & 1u)) >> 16;
    return (short)r;
}
__device__ inline float bf2f(short h) {
    return __uint_as_float(((unsigned)(unsigned short)h) << 16);
}
// min of 16 via min3-friendly tree (8 instrs)
__device__ inline float vmin16_t(f32x16 v) {
    float t1 = fminf(fminf(v[0], v[1]), v[2]);
    float t2 = fminf(fminf(v[3], v[4]), v[5]);
    float t3 = fminf(fminf(v[6], v[7]), v[8]);
    float t4 = fminf(fminf(v[9], v[10]), v[11]);
    float t5 = fminf(fminf(v[12], v[13]), v[14]);
    float u1 = fminf(fminf(t1, t2), t3);
    float u2 = fminf(fminf(t4, t5), v[15]);
    return fminf(u1, u2);
}

// K-slot map (k = 8*half + j), d = qw + pw - 2(qh+ql).(ph+pl) [ql.pl dropped]:
// A(query role) h0={-2qh(3), -2ql(3), qwh, qwl}  h1={-2qh(3), 1, 1, 0,0,0}
// B(point role) h0={ph(3), ph(3), 1, 1}          h1={pl(3), pwh, pwl, 0,0,0}
// Shared (half,j) slot space -> mapping-agnostic (r11-r14: absmax 0.0).
__global__ __launch_bounds__(256)
void chamfer_prep(const float* __restrict__ rec, const float* __restrict__ data,
                  bf16x8* __restrict__ Ar, bf16x8* __restrict__ Br,
                  bf16x8* __restrict__ Ad, bf16x8* __restrict__ Bd,
                  int N, int M, int B)
{
    const int i = blockIdx.x * 256 + threadIdx.x;
    const int tot0 = B * N, tot = tot0 + B * M;
    if (i >= tot) return;
    const short ONE = 0x3F80;
    const bool isRec = i < tot0;
    const int j = isRec ? i : i - tot0;
    const float* p = (isRec ? rec : data) + (size_t)j * 3;
    const float x = p[0], y = p[1], z = p[2];
    const float w = fmaf(x, x, fmaf(y, y, z * z));
    const short hx = f2bf(x), hy = f2bf(y), hz = f2bf(z);
    const float fx = bf2f(hx), fy = bf2f(hy), fz = bf2f(hz);
    const short nhx = f2bf(-2.f * fx), nhy = f2bf(-2.f * fy), nhz = f2bf(-2.f * fz);
    const short nlx = f2bf(-2.f * (x - fx));
    const short nly = f2bf(-2.f * (y - fy));
    const short nlz = f2bf(-2.f * (z - fz));
    const short lx = f2bf(x - fx), ly = f2bf(y - fy), lz = f2bf(z - fz);
    const short wh = f2bf(w);
    const short wl = f2bf(w - bf2f(wh));

    bf16x8 A0 = {nhx, nhy, nhz, nlx, nly, nlz, wh, wl};
    bf16x8 A1 = {nhx, nhy, nhz, ONE, ONE, 0, 0, 0};
    bf16x8 B0 = {hx, hy, hz, hx, hy, hz, ONE, ONE};
    bf16x8 B1 = {lx, ly, lz, wh, wl, 0, 0, 0};

    bf16x8* Adst = (isRec ? Ar : Ad) + 2 * (size_t)j;
    bf16x8* Bdst = (isRec ? Br : Bd) + 2 * (size_t)j;
    Adst[0] = A0; Adst[1] = A1;
    Bdst[0] = B0; Bdst[1] = B1;
}

// Stage 1: two symmetric passes (32x32x16 MFMA). 8 MFMAs per B-load
// (r12-best ratio) + 2-deep rotating B prefetch (covers ~2 iteration bodies
// of L2 latency; compiler emits counted vmcnt). Lean epilogue: <=2 D-tiles
// live, eager pairwise min3. No pins (r14: pins only add copies).
__global__ __launch_bounds__(256, 4)
void chamfer_mfma_kernel(const bf16x8* __restrict__ Ar, const bf16x8* __restrict__ Bd,
                         const bf16x8* __restrict__ Ad, const bf16x8* __restrict__ Br,
                         float* __restrict__ part_data,   // [B][N/256][M]
                         float* __restrict__ part_rec,    // [B][M/256][N]
                         int N, int M, int B)
{
    const int nSB1 = N / SROWS;
    const int G1   = B * nSB1 * NSLICE;

    const bf16x8* Ap; const bf16x8* Bp; float* outp;
    int S, T, idx;
    if ((int)blockIdx.x < G1) {
        Ap = Ar; Bp = Bd; outp = part_data; S = N; T = M; idx = blockIdx.x;
    } else {
        Ap = Ad; Bp = Br; outp = part_rec;  S = M; T = N; idx = blockIdx.x - G1;
    }
    const int nSB = S / SROWS;
    const int sl  = idx % NSLICE; idx /= NSLICE;
    const int sb  = idx % nSB;
    const int b   = idx / nSB;

    const int lane = threadIdx.x & 63, wave = threadIdx.x >> 6;
    const int c = lane & 31, h = lane >> 5;

    const bf16x8* __restrict__ Ab = Ap + 2 * ((size_t)b * S + sb * SROWS);
    const bf16x8* __restrict__ Bb = Bp + 2 * ((size_t)b * T);
    float* __restrict__ outBase = outp + ((size_t)b * nSB + sb) * T;

    bf16x8 a0 = Ab[2 * (0 * 32 + c) + h];
    bf16x8 a1 = Ab[2 * (1 * 32 + c) + h];
    bf16x8 a2 = Ab[2 * (2 * 32 + c) + h];
    bf16x8 a3 = Ab[2 * (3 * 32 + c) + h];
    bf16x8 a4 = Ab[2 * (4 * 32 + c) + h];
    bf16x8 a5 = Ab[2 * (5 * 32 + c) + h];
    bf16x8 a6 = Ab[2 * (6 * 32 + c) + h];
    bf16x8 a7 = Ab[2 * (7 * 32 + c) + h];

    f32x16 zacc;
    #pragma unroll
    for (int r = 0; r < 16; ++r) zacc[r] = 0.f;

    const int TS32   = T >> 5;
    const int TSlice = TS32 / NSLICE;            // 64 col-tiles per slice
    const int t0     = sl * TSlice + wave;
    const int tEnd   = (sl + 1) * TSlice;

    // 2-deep rotating prefetch: loads for t+4 and t+8 in flight while
    // computing t (prologue: t0 and t0+4; TSlice=64 >> 8 so no OOB here).
    bf16x8 bcur = Bb[2 * ((size_t)t0 * 32 + c) + h];
    bf16x8 bn1  = Bb[2 * ((size_t)(t0 + 4) * 32 + c) + h];

    for (int t = t0; t < tEnd; t += 4) {
        int tn = t + 8; if (tn >= tEnd) tn = t0;            // harmless reload
        bf16x8 bn2 = Bb[2 * ((size_t)tn * 32 + c) + h];     // 2-ahead

        f32x16 d0 = __builtin_amdgcn_mfma_f32_32x32x16_bf16(a0, bcur, zacc, 0, 0, 0);
        f32x16 d1 = __builtin_amdgcn_mfma_f32_32x32x16_bf16(a1, bcur, zacc, 0, 0, 0);
        f32x16 acc;
        #pragma unroll
        for (int r = 0; r < 16; ++r) acc[r] = fminf(d0[r], d1[r]);
        d0 = __builtin_amdgcn_mfma_f32_32x32x16_bf16(a2, bcur, zacc, 0, 0, 0);
        d1 = __builtin_amdgcn_mfma_f32_32x32x16_bf16(a3, bcur, zacc, 0, 0, 0);
        #pragma unroll
        for (int r = 0; r < 16; ++r) acc[r] = fminf(fminf(d0[r], d1[r]), acc[r]);
        d0 = __builtin_amdgcn_mfma_f32_32x32x16_bf16(a4, bcur, zacc, 0, 0, 0);
        d1 = __builtin_amdgcn_mfma_f32_32x32x16_bf16(a5, bcur, zacc, 0, 0, 0);
        #pragma unroll
        for (int r = 0; r < 16; ++r) acc[r] = fminf(fminf(d0[r], d1[r]), acc[r]);
        d0 = __builtin_amdgcn_mfma_f32_32x32x16_bf16(a6, bcur, zacc, 0, 0, 0);
        d1 = __builtin_amdgcn_mfma_f32_32x32x16_bf16(a7, bcur, zacc, 0, 0, 0);
        #pragma unroll
        for (int r = 0; r < 16; ++r) acc[r] = fminf(fminf(d0[r], d1[r]), acc[r]);

        float cm = vmin16_t(acc);                           // lane's 16 rows
        cm = fminf(cm, __shfl_xor(cm, 32));                 // merge halves: 256 rows
        if (lane < 32)
            outBase[(size_t)t * 32 + c] = cm;               // 128B coalesced store

        bcur = bn1; bn1 = bn2;
    }
}

// Stage 2: per point, min over the nSB stationary-block partials, clamp, sum.
__global__ __launch_bounds__(256)
void chamfer_stage2(const float* __restrict__ part_data,
                    const float* __restrict__ part_rec,
                    float* __restrict__ bsums, int N, int M, int B)
{
    __shared__ float wsum[4];
    const int gid = blockIdx.x * 256 + threadIdx.x;
    const int nD = B * M;

    const float* base; size_t stride; int depth;
    if (gid < nD) {
        const int b = gid / M, col = gid - b * M;
        base = part_data + ((size_t)b * (N / SROWS)) * M + col;
        stride = M; depth = N / SROWS;
    } else {
        const int g = gid - nD;
        const int b = g / N, col = g - b * N;
        base = part_rec + ((size_t)b * (M / SROWS)) * N + col;
        stride = N; depth = M / SROWS;
    }
    float m0 = 3.4e38f, m1 = 3.4e38f, m2 = 3.4e38f, m3 = 3.4e38f;
    int s = 0;
    for (; s + 4 <= depth; s += 4) {
        m0 = fminf(m0, base[(s + 0) * stride]);
        m1 = fminf(m1, base[(s + 1) * stride]);
        m2 = fminf(m2, base[(s + 2) * stride]);
        m3 = fminf(m3, base[(s + 3) * stride]);
    }
    for (; s < depth; ++s) m0 = fminf(m0, base[s * stride]);
    float d = fmaxf(fminf(fminf(m0, m1), fminf(m2, m3)), 0.f);

    for (int off = 32; off; off >>= 1) d += __shfl_down(d, off);
    if ((threadIdx.x & 63) == 0) wsum[threadIdx.x >> 6] = d;
    __syncthreads();
    if (threadIdx.x == 0)
        bsums[blockIdx.x] = wsum[0] + wsum[1] + wsum[2] + wsum[3];
}

// Finalize: mean_b( max(recsum_b/N, datasum_b/M) )
__global__ __launch_bounds__(256)
void chamfer_finalize(const float* __restrict__ bsums, float* __restrict__ out,
                      int N, int M, int B)
{
    __shared__ float smem[512];
    __shared__ float seg[16];
    const int ncD = M >> 8, ncR = N >> 8;       // stage2 blocks per batch
    const int nD  = B * ncD, ntot = nD + B * ncR;
    const int tid = threadIdx.x;
    for (int i = tid; i < ntot; i += 256) smem[i] = bsums[i];
    __syncthreads();
    if (tid < 2 * B) {
        const int dir = tid / B, bb = tid % B;   // dir0 = data, dir1 = rec
        float s = 0.f;
        if (dir == 0) for (int i = 0; i < ncD; ++i) s += smem[bb * ncD + i];
        else          for (int i = 0; i < ncR; ++i) s += smem[nD + bb * ncR + i];
        seg[tid] = s;
    }
    __syncthreads();
    if (tid == 0) {
        float acc = 0.f;
        for (int bb = 0; bb < B; ++bb)
            acc += fmaxf(seg[B + bb] / (float)N, seg[bb] / (float)M);
        out[0] = acc / (float)B;
    }
}

extern "C" void kernel_launch(void* const* d_in, const int* in_sizes, int n_in,
                              void* d_out, int out_size, void* d_ws, size_t ws_size,
                              hipStream_t stream)
{
    const float* rec  = (const float*)d_in[0];
    const float* data = (const float*)d_in[1];
    const int B = 4;
    const int N = in_sizes[0] / (B * 3);
    const int M = in_sizes[1] / (B * 3);
    const int tot = B * (N + M);

    // ws: Ar 1MB | Br 1MB | Ad 1MB | Bd 1MB | part_data 4.2MB | part_rec 4.2MB
    char* w = (char*)d_ws;
    bf16x8* Ar = (bf16x8*)w;  w += (size_t)B * N * 2 * sizeof(bf16x8);
    bf16x8* Br = (bf16x8*)w;  w += (size_t)B * N * 2 * sizeof(bf16x8);
    bf16x8* Ad = (bf16x8*)w;  w += (size_t)B * M * 2 * sizeof(bf16x8);
    bf16x8* Bd = (bf16x8*)w;  w += (size_t)B * M * 2 * sizeof(bf16x8);
    float* part_data = (float*)w;  w += (size_t)B * (N / SROWS) * M * sizeof(float);
    float* part_rec  = (float*)w;  w += (size_t)B * (M / SROWS) * N * sizeof(float);
    float* bsums = (float*)w;

    chamfer_prep<<<(tot + 255) / 256, 256, 0, stream>>>(rec, data, Ar, Br, Ad, Bd,
                                                        N, M, B);
    const int G = B * (N / SROWS) * NSLICE + B * (M / SROWS) * NSLICE;  // 1024
    chamfer_mfma_kernel<<<G, 256, 0, stream>>>(Ar, Bd, Ad, Br,
                                               part_data, part_rec, N, M, B);
    chamfer_stage2<<<tot / 256, 256, 0, stream>>>(part_data, part_rec, bsums,
                                                  N, M, B);
    chamfer_finalize<<<1, 256, 0, stream>>>(bsums, (float*)d_out, N, M, B);
}